// Round 2
// baseline (61.878 us; speedup 1.0000x reference)
//
#include <hip/hip_runtime.h>
#include <hip/hip_bf16.h>

#define N_NODES 65536
#define NUM_G   64
#define GSIZE   1024
#define DIM     64

using frag_ab = __attribute__((ext_vector_type(8))) short;   // 8 bf16 (4 VGPRs)
using f32x4   = __attribute__((ext_vector_type(4))) float;   // 4 fp32 accum

__device__ __forceinline__ unsigned short f2bf(float x) {
    union { float f; unsigned int u; } v; v.f = x;
    unsigned int r = v.u + 0x7FFFu + ((v.u >> 16) & 1u);   // RNE
    return (unsigned short)(r >> 16);
}

// Kernel 1: fp32 row-normalize z1,z2 -> bf16 copies; pos = (z1n . z2n) * inv_t (fp32).
__global__ __launch_bounds__(256) void normalize_k(
    const float* __restrict__ z1, const float* __restrict__ z2,
    unsigned short* __restrict__ z1n, unsigned short* __restrict__ z2n,
    float* __restrict__ pos)
{
    int tid = threadIdx.x;
    int row = blockIdx.x * 16 + (tid >> 4);
    int l4  = tid & 15;
    float4 v1 = *((const float4*)(z1 + (size_t)row * DIM) + l4);
    float4 v2 = *((const float4*)(z2 + (size_t)row * DIM) + l4);
    float ss1 = v1.x*v1.x + v1.y*v1.y + v1.z*v1.z + v1.w*v1.w;
    float ss2 = v2.x*v2.x + v2.y*v2.y + v2.z*v2.z + v2.w*v2.w;
    float dt  = v1.x*v2.x + v1.y*v2.y + v1.z*v2.z + v1.w*v2.w;
    #pragma unroll
    for (int m = 1; m < 16; m <<= 1) {
        ss1 += __shfl_xor(ss1, m);
        ss2 += __shfl_xor(ss2, m);
        dt  += __shfl_xor(dt,  m);
    }
    float in1 = 1.0f / sqrtf(ss1);
    float in2 = 1.0f / sqrtf(ss2);
    ushort4 o1, o2;
    o1.x = f2bf(v1.x*in1); o1.y = f2bf(v1.y*in1); o1.z = f2bf(v1.z*in1); o1.w = f2bf(v1.w*in1);
    o2.x = f2bf(v2.x*in2); o2.y = f2bf(v2.y*in2); o2.z = f2bf(v2.z*in2); o2.w = f2bf(v2.w*in2);
    *((ushort4*)(z1n + (size_t)row * DIM) + l4) = o1;
    *((ushort4*)(z2n + (size_t)row * DIM) + l4) = o2;
    if (l4 == 0) pos[row] = dt * in1 * in2 * 2.0f;   // inv_t = 2
}

// Kernel 2: software-pipelined. MFMAs of panel p overlap exp-VALU of panel p-1
// (independent C register sets Ce/Co, static indexing). LDS panels 64x64 bf16,
// XOR-swizzled both sides, double-buffered, reg-staged prefetch 2 panels ahead.
__global__ __launch_bounds__(256, 2) void grace_main_k(
    const unsigned short* __restrict__ z1n,
    const unsigned short* __restrict__ z2n,
    const float* __restrict__ pos,
    float* __restrict__ partials)
{
    __shared__ unsigned short smem[2][64 * 64];   // 2 x 8KB panels
    __shared__ float red[4];

    int tid = threadIdx.x;
    int g = blockIdx.x >> 3, stripe = blockIdx.x & 7;
    int w = tid >> 6, l = tid & 63;
    const unsigned short* z1g = z1n + (size_t)g * GSIZE * DIM;
    const unsigned short* z2g = z2n + (size_t)g * GSIZE * DIM;
    int rowBase = stripe * 128 + w * 32;

    // A fragments: rows rowBase..+31, layout A[l&15][(l>>4)*8 + e] per 32-k chunk
    int ar = l & 15, ak = (l >> 4) * 8;
    frag_ab a00 = *(const frag_ab*)(z1g + (rowBase +  0 + ar) * DIM +  0 + ak);
    frag_ab a01 = *(const frag_ab*)(z1g + (rowBase +  0 + ar) * DIM + 32 + ak);
    frag_ab a10 = *(const frag_ab*)(z1g + (rowBase + 16 + ar) * DIM +  0 + ak);
    frag_ab a11 = *(const frag_ab*)(z1g + (rowBase + 16 + ar) * DIM + 32 + ak);

    float expacc[2][4] = {};
    f32x4 Ce[4][2], Co[4][2];   // pipelined C tiles: [ct][row-tile]

    // staging: 512 x 16B per panel, 2 per thread. e -> col=e>>3, slot=e&7
    int e0 = tid, e1 = tid + 256;
    int wcol0 = e0 >> 3, wslot0 = e0 & 7;
    int wcol1 = e1 >> 3, wslot1 = e1 & 7;
    int off0 = ((wcol0 << 7) + (wslot0 << 4)) ^ ((wcol0 & 7) << 4);
    int off1 = ((wcol1 << 7) + (wslot1 << 4)) ^ ((wcol1 & 7) << 4);

    auto src_ptr = [&](int p, int col, int slot) -> const int4* {
        const unsigned short* s = (p < 16) ? z2g : z1g;
        return (const int4*)(s + ((p & 15) * 64 + col) * DIM + slot * 8);
    };

    // B-frag read: col = ct*16 + (l&15), slot = c*4 + (l>>4), same XOR (col&7 == l&7)
    int bcol = l & 15, bgrp = l >> 4, bx = (l & 7) << 4;

    auto panel_mfma = [&](f32x4 (&C)[4][2], const unsigned short* buf) {
        const char* base = (const char*)buf;
        #pragma unroll
        for (int ct = 0; ct < 4; ++ct) {
            int col = ct * 16 + bcol;
            int boff0 = ((col << 7) + (bgrp << 4)) ^ bx;
            int boff1 = ((col << 7) + ((4 + bgrp) << 4)) ^ bx;
            frag_ab b0 = *(const frag_ab*)(base + boff0);
            frag_ab b1 = *(const frag_ab*)(base + boff1);
            f32x4 z = {0.f, 0.f, 0.f, 0.f};
            f32x4 t0 = __builtin_amdgcn_mfma_f32_16x16x32_bf16(a00, b0, z, 0, 0, 0);
            f32x4 t1 = __builtin_amdgcn_mfma_f32_16x16x32_bf16(a10, b0, z, 0, 0, 0);
            C[ct][0] = __builtin_amdgcn_mfma_f32_16x16x32_bf16(a01, b1, t0, 0, 0, 0);
            C[ct][1] = __builtin_amdgcn_mfma_f32_16x16x32_bf16(a11, b1, t1, 0, 0, 0);
        }
    };

    const float K1 = 2.8853900817779268f;   // 2 * log2(e)  (inv_t / tau folded)
    const float K0 = -2.8853900817779268f;  // -2 * log2(e) (fixed shift m=2)
    auto acc_exp = [&](f32x4 (&C)[4][2]) {
        #pragma unroll
        for (int ct = 0; ct < 4; ++ct) {
            #pragma unroll
            for (int r = 0; r < 4; ++r) {
                expacc[0][r] += exp2f(fmaf(C[ct][0][r], K1, K0));
                expacc[1][r] += exp2f(fmaf(C[ct][1][r], K1, K0));
            }
        }
    };

    // prologue: stage panel 0 -> buf0, prefetch panel 1 into regs
    int4 pre0 = *src_ptr(0, wcol0, wslot0);
    int4 pre1 = *src_ptr(0, wcol1, wslot1);
    *(int4*)((char*)smem[0] + off0) = pre0;
    *(int4*)((char*)smem[0] + off1) = pre1;
    pre0 = *src_ptr(1, wcol0, wslot0);
    pre1 = *src_ptr(1, wcol1, wslot1);
    __syncthreads();

    #pragma unroll 1
    for (int i = 0; i < 16; ++i) {
        // EVEN panel 2i from buf0
        panel_mfma(Ce, smem[0]);
        *(int4*)((char*)smem[1] + off0) = pre0;   // publish panel 2i+1 (buf1 readers barriered)
        *(int4*)((char*)smem[1] + off1) = pre1;
        if (i < 15) {
            pre0 = *src_ptr(2 * i + 2, wcol0, wslot0);
            pre1 = *src_ptr(2 * i + 2, wcol1, wslot1);
        }
        if (i > 0) acc_exp(Co);                   // VALU for panel 2i-1 overlaps MFMA of 2i
        __syncthreads();
        // ODD panel 2i+1 from buf1
        panel_mfma(Co, smem[1]);
        if (i < 15) {
            *(int4*)((char*)smem[0] + off0) = pre0;  // publish panel 2i+2
            *(int4*)((char*)smem[0] + off1) = pre1;
            pre0 = *src_ptr(2 * i + 3, wcol0, wslot0);
            pre1 = *src_ptr(2 * i + 3, wcol1, wslot1);
        }
        acc_exp(Ce);                              // VALU for panel 2i overlaps MFMA of 2i+1
        if (i < 15) __syncthreads();
    }
    acc_exp(Co);                                  // epilogue: panel 31

    // Row reduce: C/D row = (l>>4)*4 + r, col = l&15 -> sum across low-4 lane bits
    float part = 0.f;
    #pragma unroll
    for (int t = 0; t < 2; ++t) {
        #pragma unroll
        for (int r = 0; r < 4; ++r) {
            float s = expacc[t][r];
            s += __shfl_xor(s, 1); s += __shfl_xor(s, 2);
            s += __shfl_xor(s, 4); s += __shfl_xor(s, 8);
            if ((l & 15) == 0) {
                int row = rowBase + t * 16 + (l >> 4) * 4 + r;
                int node = g * GSIZE + row;
                part += 2.0f + __logf(s - 1.0f) - pos[node];  // -1: excluded sim11 diag
            }
        }
    }
    #pragma unroll
    for (int m = 1; m < 64; m <<= 1) part += __shfl_xor(part, m);
    if (l == 0) red[w] = part;
    __syncthreads();
    if (tid == 0) partials[blockIdx.x] = red[0] + red[1] + red[2] + red[3];
}

// Kernel 3: deterministic 512 -> 1 reduce, mean over nodes.
__global__ __launch_bounds__(256) void final_reduce_k(
    const float* __restrict__ partials, float* __restrict__ out)
{
    int tid = threadIdx.x;
    float s = partials[tid] + partials[tid + 256];
    #pragma unroll
    for (int m = 1; m < 64; m <<= 1) s += __shfl_xor(s, m);
    __shared__ float red[4];
    if ((tid & 63) == 0) red[tid >> 6] = s;
    __syncthreads();
    if (tid == 0) out[0] = (red[0] + red[1] + red[2] + red[3]) * (1.0f / N_NODES);
}

extern "C" void kernel_launch(void* const* d_in, const int* in_sizes, int n_in,
                              void* d_out, int out_size, void* d_ws, size_t ws_size,
                              hipStream_t stream)
{
    const float* z1 = (const float*)d_in[0];
    const float* z2 = (const float*)d_in[1];
    char* ws = (char*)d_ws;
    unsigned short* z1n = (unsigned short*)ws;                       // 8 MB
    unsigned short* z2n = (unsigned short*)(ws + 8388608);           // 8 MB
    float* pos          = (float*)(ws + 16777216);                   // 256 KB
    float* partials     = (float*)(ws + 17039360);                   // 2 KB

    normalize_k<<<dim3(N_NODES / 16), dim3(256), 0, stream>>>(z1, z2, z1n, z2n, pos);
    grace_main_k<<<dim3(NUM_G * 8), dim3(256), 0, stream>>>(z1n, z2n, pos, partials);
    final_reduce_k<<<dim3(1), dim3(256), 0, stream>>>(partials, (float*)d_out);
}

// Round 3
// 46.458 us; speedup vs baseline: 1.3319x; 1.3319x over previous
//
#include <hip/hip_runtime.h>
#include <hip/hip_bf16.h>

#define N_NODES 65536
#define NUM_G   64
#define GSIZE   1024
#define DIM     64

using frag_ab = __attribute__((ext_vector_type(8))) short;   // 8 bf16 (4 VGPRs)
using f32x4   = __attribute__((ext_vector_type(4))) float;   // 4 fp32 accum

__device__ __forceinline__ unsigned short f2bf(float x) {
    union { float f; unsigned int u; } v; v.f = x;
    unsigned int r = v.u + 0x7FFFu + ((v.u >> 16) & 1u);   // RNE
    return (unsigned short)(r >> 16);
}

// Kernel 1: fp32 row-normalize z1,z2 -> bf16 copies; pos = (z1n . z2n) * inv_t (fp32).
__global__ __launch_bounds__(256) void normalize_k(
    const float* __restrict__ z1, const float* __restrict__ z2,
    unsigned short* __restrict__ z1n, unsigned short* __restrict__ z2n,
    float* __restrict__ pos)
{
    int tid = threadIdx.x;
    int row = blockIdx.x * 16 + (tid >> 4);
    int l4  = tid & 15;
    float4 v1 = *((const float4*)(z1 + (size_t)row * DIM) + l4);
    float4 v2 = *((const float4*)(z2 + (size_t)row * DIM) + l4);
    float ss1 = v1.x*v1.x + v1.y*v1.y + v1.z*v1.z + v1.w*v1.w;
    float ss2 = v2.x*v2.x + v2.y*v2.y + v2.z*v2.z + v2.w*v2.w;
    float dt  = v1.x*v2.x + v1.y*v2.y + v1.z*v2.z + v1.w*v2.w;
    #pragma unroll
    for (int m = 1; m < 16; m <<= 1) {
        ss1 += __shfl_xor(ss1, m);
        ss2 += __shfl_xor(ss2, m);
        dt  += __shfl_xor(dt,  m);
    }
    float in1 = 1.0f / sqrtf(ss1);
    float in2 = 1.0f / sqrtf(ss2);
    ushort4 o1, o2;
    o1.x = f2bf(v1.x*in1); o1.y = f2bf(v1.y*in1); o1.z = f2bf(v1.z*in1); o1.w = f2bf(v1.w*in1);
    o2.x = f2bf(v2.x*in2); o2.y = f2bf(v2.y*in2); o2.z = f2bf(v2.z*in2); o2.w = f2bf(v2.w*in2);
    *((ushort4*)(z1n + (size_t)row * DIM) + l4) = o1;
    *((ushort4*)(z2n + (size_t)row * DIM) + l4) = o2;
    if (l4 == 0) pos[row] = dt * in1 * in2 * 2.0f;   // inv_t = 2
}

// Kernel 2: MFMA panels + native v_exp_f32 accumulate, Ce/Co software pipeline.
// Block swizzle: all 8 stripes of a graph land on ONE XCD (round-robin n%8 model)
// so the graph's 256KB of panels is fetched once into that XCD's 4MB L2.
__global__ __launch_bounds__(256, 2) void grace_main_k(
    const unsigned short* __restrict__ z1n,
    const unsigned short* __restrict__ z2n,
    const float* __restrict__ pos,
    float* __restrict__ partials)
{
    __shared__ unsigned short smem[2][64 * 64];   // 2 x 8KB panels
    __shared__ float red[4];

    int tid = threadIdx.x;
    int n = blockIdx.x;
    int g = (n & 7) + 8 * (n >> 6);   // graph: all its blocks share XCD (n%8)
    int stripe = (n >> 3) & 7;
    int w = tid >> 6, l = tid & 63;
    const unsigned short* z1g = z1n + (size_t)g * GSIZE * DIM;
    const unsigned short* z2g = z2n + (size_t)g * GSIZE * DIM;
    int rowBase = stripe * 128 + w * 32;

    // A fragments: rows rowBase..+31, layout A[l&15][(l>>4)*8 + e] per 32-k chunk
    int ar = l & 15, ak = (l >> 4) * 8;
    frag_ab a00 = *(const frag_ab*)(z1g + (rowBase +  0 + ar) * DIM +  0 + ak);
    frag_ab a01 = *(const frag_ab*)(z1g + (rowBase +  0 + ar) * DIM + 32 + ak);
    frag_ab a10 = *(const frag_ab*)(z1g + (rowBase + 16 + ar) * DIM +  0 + ak);
    frag_ab a11 = *(const frag_ab*)(z1g + (rowBase + 16 + ar) * DIM + 32 + ak);

    float expacc[2][4] = {};
    f32x4 Ce[4][2], Co[4][2];   // pipelined C tiles: [ct][row-tile]

    // staging: 512 x 16B per panel, 2 per thread. e -> col=e>>3, slot=e&7
    int e0 = tid, e1 = tid + 256;
    int wcol0 = e0 >> 3, wslot0 = e0 & 7;
    int wcol1 = e1 >> 3, wslot1 = e1 & 7;
    int off0 = ((wcol0 << 7) + (wslot0 << 4)) ^ ((wcol0 & 7) << 4);
    int off1 = ((wcol1 << 7) + (wslot1 << 4)) ^ ((wcol1 & 7) << 4);

    auto src_ptr = [&](int p, int col, int slot) -> const int4* {
        const unsigned short* s = (p < 16) ? z2g : z1g;
        return (const int4*)(s + ((p & 15) * 64 + col) * DIM + slot * 8);
    };

    // B-frag read: col = ct*16 + (l&15), slot = c*4 + (l>>4), same XOR (col&7 == l&7)
    int bcol = l & 15, bgrp = l >> 4, bx = (l & 7) << 4;

    auto panel_mfma = [&](f32x4 (&C)[4][2], const unsigned short* buf) {
        const char* base = (const char*)buf;
        #pragma unroll
        for (int ct = 0; ct < 4; ++ct) {
            int col = ct * 16 + bcol;
            int boff0 = ((col << 7) + (bgrp << 4)) ^ bx;
            int boff1 = ((col << 7) + ((4 + bgrp) << 4)) ^ bx;
            frag_ab b0 = *(const frag_ab*)(base + boff0);
            frag_ab b1 = *(const frag_ab*)(base + boff1);
            f32x4 z = {0.f, 0.f, 0.f, 0.f};
            f32x4 t0 = __builtin_amdgcn_mfma_f32_16x16x32_bf16(a00, b0, z, 0, 0, 0);
            f32x4 t1 = __builtin_amdgcn_mfma_f32_16x16x32_bf16(a10, b0, z, 0, 0, 0);
            C[ct][0] = __builtin_amdgcn_mfma_f32_16x16x32_bf16(a01, b1, t0, 0, 0, 0);
            C[ct][1] = __builtin_amdgcn_mfma_f32_16x16x32_bf16(a11, b1, t1, 0, 0, 0);
        }
    };

    const float K1 = 2.8853900817779268f;   // 2 * log2(e)   (inv_t=2 folded)
    const float K0 = -2.8853900817779268f;  // -2 * log2(e)  (fixed shift m=2)
    auto acc_exp = [&](f32x4 (&C)[4][2]) {
        #pragma unroll
        for (int ct = 0; ct < 4; ++ct) {
            #pragma unroll
            for (int r = 0; r < 4; ++r) {
                expacc[0][r] += __builtin_amdgcn_exp2f(fmaf(C[ct][0][r], K1, K0));
                expacc[1][r] += __builtin_amdgcn_exp2f(fmaf(C[ct][1][r], K1, K0));
            }
        }
    };

    // prologue: stage panel 0 -> buf0, prefetch panel 1 into regs
    int4 pre0 = *src_ptr(0, wcol0, wslot0);
    int4 pre1 = *src_ptr(0, wcol1, wslot1);
    *(int4*)((char*)smem[0] + off0) = pre0;
    *(int4*)((char*)smem[0] + off1) = pre1;
    pre0 = *src_ptr(1, wcol0, wslot0);
    pre1 = *src_ptr(1, wcol1, wslot1);
    __syncthreads();

    #pragma unroll 1
    for (int i = 0; i < 16; ++i) {
        // EVEN panel 2i from buf0
        panel_mfma(Ce, smem[0]);
        *(int4*)((char*)smem[1] + off0) = pre0;   // publish panel 2i+1 (buf1 readers barriered)
        *(int4*)((char*)smem[1] + off1) = pre1;
        if (i < 15) {
            pre0 = *src_ptr(2 * i + 2, wcol0, wslot0);
            pre1 = *src_ptr(2 * i + 2, wcol1, wslot1);
        }
        if (i > 0) acc_exp(Co);                   // VALU for panel 2i-1 overlaps MFMA of 2i
        __syncthreads();
        // ODD panel 2i+1 from buf1
        panel_mfma(Co, smem[1]);
        if (i < 15) {
            *(int4*)((char*)smem[0] + off0) = pre0;  // publish panel 2i+2
            *(int4*)((char*)smem[0] + off1) = pre1;
            pre0 = *src_ptr(2 * i + 3, wcol0, wslot0);
            pre1 = *src_ptr(2 * i + 3, wcol1, wslot1);
        }
        acc_exp(Ce);                              // VALU for panel 2i overlaps MFMA of 2i+1
        if (i < 15) __syncthreads();
    }
    acc_exp(Co);                                  // epilogue: panel 31

    // Row reduce: C/D row = (l>>4)*4 + r, col = l&15 -> sum across low-4 lane bits
    float part = 0.f;
    #pragma unroll
    for (int t = 0; t < 2; ++t) {
        #pragma unroll
        for (int r = 0; r < 4; ++r) {
            float s = expacc[t][r];
            s += __shfl_xor(s, 1); s += __shfl_xor(s, 2);
            s += __shfl_xor(s, 4); s += __shfl_xor(s, 8);
            if ((l & 15) == 0) {
                int row = rowBase + t * 16 + (l >> 4) * 4 + r;
                int node = g * GSIZE + row;
                part += 2.0f + __logf(s - 1.0f) - pos[node];  // -1: excluded sim11 diag
            }
        }
    }
    #pragma unroll
    for (int m = 1; m < 64; m <<= 1) part += __shfl_xor(part, m);
    if (l == 0) red[w] = part;
    __syncthreads();
    if (tid == 0) partials[blockIdx.x] = red[0] + red[1] + red[2] + red[3];
}

// Kernel 3: deterministic 512 -> 1 reduce, mean over nodes.
__global__ __launch_bounds__(256) void final_reduce_k(
    const float* __restrict__ partials, float* __restrict__ out)
{
    int tid = threadIdx.x;
    float s = partials[tid] + partials[tid + 256];
    #pragma unroll
    for (int m = 1; m < 64; m <<= 1) s += __shfl_xor(s, m);
    __shared__ float red[4];
    if ((tid & 63) == 0) red[tid >> 6] = s;
    __syncthreads();
    if (tid == 0) out[0] = (red[0] + red[1] + red[2] + red[3]) * (1.0f / N_NODES);
}

extern "C" void kernel_launch(void* const* d_in, const int* in_sizes, int n_in,
                              void* d_out, int out_size, void* d_ws, size_t ws_size,
                              hipStream_t stream)
{
    const float* z1 = (const float*)d_in[0];
    const float* z2 = (const float*)d_in[1];
    char* ws = (char*)d_ws;
    unsigned short* z1n = (unsigned short*)ws;                       // 8 MB
    unsigned short* z2n = (unsigned short*)(ws + 8388608);           // 8 MB
    float* pos          = (float*)(ws + 16777216);                   // 256 KB
    float* partials     = (float*)(ws + 17039360);                   // 2 KB

    normalize_k<<<dim3(N_NODES / 16), dim3(256), 0, stream>>>(z1, z2, z1n, z2n, pos);
    grace_main_k<<<dim3(NUM_G * 8), dim3(256), 0, stream>>>(z1n, z2n, pos, partials);
    final_reduce_k<<<dim3(1), dim3(256), 0, stream>>>(partials, (float*)d_out);
}

// Round 4
// 45.477 us; speedup vs baseline: 1.3606x; 1.0216x over previous
//
#include <hip/hip_runtime.h>
#include <hip/hip_bf16.h>

#define N_NODES 65536
#define NUM_G   64
#define GSIZE   1024
#define DIM     64

using frag_ab = __attribute__((ext_vector_type(8))) short;   // 8 bf16 (4 VGPRs)
using f32x4   = __attribute__((ext_vector_type(4))) float;   // 4 fp32 accum

__device__ __forceinline__ unsigned short f2bf(float x) {
    union { float f; unsigned int u; } v; v.f = x;
    unsigned int r = v.u + 0x7FFFu + ((v.u >> 16) & 1u);   // RNE
    return (unsigned short)(r >> 16);
}

// Kernel 1: fp32 row-normalize z1,z2 -> bf16 copies; pos = (z1n . z2n) * inv_t (fp32).
__global__ __launch_bounds__(256) void normalize_k(
    const float* __restrict__ z1, const float* __restrict__ z2,
    unsigned short* __restrict__ z1n, unsigned short* __restrict__ z2n,
    float* __restrict__ pos)
{
    int tid = threadIdx.x;
    int row = blockIdx.x * 16 + (tid >> 4);
    int l4  = tid & 15;
    float4 v1 = *((const float4*)(z1 + (size_t)row * DIM) + l4);
    float4 v2 = *((const float4*)(z2 + (size_t)row * DIM) + l4);
    float ss1 = v1.x*v1.x + v1.y*v1.y + v1.z*v1.z + v1.w*v1.w;
    float ss2 = v2.x*v2.x + v2.y*v2.y + v2.z*v2.z + v2.w*v2.w;
    float dt  = v1.x*v2.x + v1.y*v2.y + v1.z*v2.z + v1.w*v2.w;
    #pragma unroll
    for (int m = 1; m < 16; m <<= 1) {
        ss1 += __shfl_xor(ss1, m);
        ss2 += __shfl_xor(ss2, m);
        dt  += __shfl_xor(dt,  m);
    }
    float in1 = 1.0f / sqrtf(ss1);
    float in2 = 1.0f / sqrtf(ss2);
    ushort4 o1, o2;
    o1.x = f2bf(v1.x*in1); o1.y = f2bf(v1.y*in1); o1.z = f2bf(v1.z*in1); o1.w = f2bf(v1.w*in1);
    o2.x = f2bf(v2.x*in2); o2.y = f2bf(v2.y*in2); o2.z = f2bf(v2.z*in2); o2.w = f2bf(v2.w*in2);
    *((ushort4*)(z1n + (size_t)row * DIM) + l4) = o1;
    *((ushort4*)(z2n + (size_t)row * DIM) + l4) = o2;
    if (l4 == 0) pos[row] = dt * in1 * in2 * 2.0f;   // inv_t = 2
}

// Kernel 2: 512 threads (8 waves x 16 rows), panel-PAIR double buffer (16KB each),
// ONE barrier per pair. Issue-early global prefetch, write-late LDS publish.
// XCD swizzle: all 8 blocks of a graph on one XCD (n%8 round-robin model).
__global__ __launch_bounds__(512, 4) void grace_main_k(
    const unsigned short* __restrict__ z1n,
    const unsigned short* __restrict__ z2n,
    const float* __restrict__ pos,
    float* __restrict__ partials)
{
    __shared__ unsigned short smem[2][128 * 64];   // 2 x 16KB pair-buffers
    __shared__ float red[8];

    int tid = threadIdx.x;
    int n = blockIdx.x;
    int g = (n & 7) + 8 * (n >> 6);   // graph: all its blocks share XCD (n%8)
    int stripe = (n >> 3) & 7;
    int w = tid >> 6, l = tid & 63;
    const unsigned short* z1g = z1n + (size_t)g * GSIZE * DIM;
    const unsigned short* z2g = z2n + (size_t)g * GSIZE * DIM;
    int rowBase = stripe * 128 + w * 16;

    // A fragments: 16 rows per wave, layout A[l&15][(l>>4)*8 + e] per 32-k chunk
    int ar = l & 15, ak = (l >> 4) * 8;
    frag_ab a0 = *(const frag_ab*)(z1g + (rowBase + ar) * DIM +  0 + ak);
    frag_ab a1 = *(const frag_ab*)(z1g + (rowBase + ar) * DIM + 32 + ak);

    float expacc[4] = {};

    // staging: pair = 128 cols x 8 slots of 16B = 1024 chunks; 2 per thread
    int col0 = tid >> 3, slot = tid & 7;          // e0 = tid      -> cols 0..63
    int col1 = col0 + 64;                         // e1 = tid+512  -> cols 64..127
    int off0 = ((col0 << 7) + (slot << 4)) ^ ((col0 & 7) << 4);
    int off1 = ((col1 << 7) + (slot << 4)) ^ ((col1 & 7) << 4);   // col1&7 == col0&7

    // global source for pair p, local col c, slot s: virtual col j = p*128+c over [z2 | z1]
    auto src_ptr = [&](int p, int c) -> const int4* {
        int j = p * 128 + c;
        const unsigned short* s = (j < 1024) ? (z2g + j * DIM) : (z1g + (j - 1024) * DIM);
        return (const int4*)(s + slot * 8);
    };

    // B-frag read: tile ct in [0,8): col = ct*16 + (l&15); col&7 == l&7
    int bcol = l & 15, bgrp = l >> 4, bx = (l & 7) << 4;

    const float K1 = 2.8853900817779268f;   // 2 * log2(e)   (inv_t=2 folded)
    const float K0 = -2.8853900817779268f;  // -2 * log2(e)  (fixed shift m=2)

    // prologue: stage pair 0 -> buf0
    int4 pre0 = *src_ptr(0, col0);
    int4 pre1 = *src_ptr(0, col1);
    *(int4*)((char*)smem[0] + off0) = pre0;
    *(int4*)((char*)smem[0] + off1) = pre1;
    __syncthreads();

    #pragma unroll 1
    for (int i = 0; i < 16; ++i) {
        if (i < 15) {                         // issue next-pair loads EARLY
            pre0 = *src_ptr(i + 1, col0);
            pre1 = *src_ptr(i + 1, col1);
        }
        const char* base = (const char*)smem[i & 1];
        #pragma unroll
        for (int ct = 0; ct < 8; ++ct) {
            int col = ct * 16 + bcol;
            frag_ab b0 = *(const frag_ab*)(base + (((col << 7) + (bgrp << 4)) ^ bx));
            frag_ab b1 = *(const frag_ab*)(base + (((col << 7) + ((4 + bgrp) << 4)) ^ bx));
            f32x4 z = {0.f, 0.f, 0.f, 0.f};
            f32x4 c = __builtin_amdgcn_mfma_f32_16x16x32_bf16(a0, b0, z, 0, 0, 0);
            c = __builtin_amdgcn_mfma_f32_16x16x32_bf16(a1, b1, c, 0, 0, 0);
            #pragma unroll
            for (int r = 0; r < 4; ++r)
                expacc[r] += __builtin_amdgcn_exp2f(fmaf(c[r], K1, K0));
        }
        if (i < 15) {                         // publish LATE into the other buffer
            char* wb = (char*)smem[(i + 1) & 1];
            *(int4*)(wb + off0) = pre0;       // safe: barrier at end of i-1 drained
            *(int4*)(wb + off1) = pre1;       //       all reads of this buffer
            __syncthreads();
        }
    }

    // Row reduce: C/D row = (l>>4)*4 + r, col = l&15 -> sum across low-4 lane bits
    float part = 0.f;
    #pragma unroll
    for (int r = 0; r < 4; ++r) {
        float s = expacc[r];
        s += __shfl_xor(s, 1); s += __shfl_xor(s, 2);
        s += __shfl_xor(s, 4); s += __shfl_xor(s, 8);
        if ((l & 15) == 0) {
            int row = rowBase + (l >> 4) * 4 + r;
            part += 2.0f + __logf(s - 1.0f) - pos[g * GSIZE + row];  // -1: sim11 diag
        }
    }
    #pragma unroll
    for (int m = 1; m < 64; m <<= 1) part += __shfl_xor(part, m);
    if (l == 0) red[w] = part;
    __syncthreads();
    if (tid == 0) {
        float s = 0.f;
        #pragma unroll
        for (int k = 0; k < 8; ++k) s += red[k];
        partials[blockIdx.x] = s;
    }
}

// Kernel 3: deterministic 512 -> 1 reduce, mean over nodes.
__global__ __launch_bounds__(256) void final_reduce_k(
    const float* __restrict__ partials, float* __restrict__ out)
{
    int tid = threadIdx.x;
    float s = partials[tid] + partials[tid + 256];
    #pragma unroll
    for (int m = 1; m < 64; m <<= 1) s += __shfl_xor(s, m);
    __shared__ float red[4];
    if ((tid & 63) == 0) red[tid >> 6] = s;
    __syncthreads();
    if (tid == 0) out[0] = (red[0] + red[1] + red[2] + red[3]) * (1.0f / N_NODES);
}

extern "C" void kernel_launch(void* const* d_in, const int* in_sizes, int n_in,
                              void* d_out, int out_size, void* d_ws, size_t ws_size,
                              hipStream_t stream)
{
    const float* z1 = (const float*)d_in[0];
    const float* z2 = (const float*)d_in[1];
    char* ws = (char*)d_ws;
    unsigned short* z1n = (unsigned short*)ws;                       // 8 MB
    unsigned short* z2n = (unsigned short*)(ws + 8388608);           // 8 MB
    float* pos          = (float*)(ws + 16777216);                   // 256 KB
    float* partials     = (float*)(ws + 17039360);                   // 2 KB

    normalize_k<<<dim3(N_NODES / 16), dim3(256), 0, stream>>>(z1, z2, z1n, z2n, pos);
    grace_main_k<<<dim3(NUM_G * 8), dim3(512), 0, stream>>>(z1n, z2n, pos, partials);
    final_reduce_k<<<dim3(1), dim3(256), 0, stream>>>(partials, (float*)d_out);
}